// Round 10
// baseline (2813.274 us; speedup 1.0000x reference)
//
#include <hip/hip_runtime.h>

typedef unsigned long long u64;
typedef unsigned int u32;

#define W1H 1023   // after conv1+pool
#define W2H 1021   // after conv2
#define W3H 1019   // after conv3
#define NPIX (W3H * W3H)          // 1,038,361 < 2^20
#define IDXMASK 0xFFFFFull
#define PSTR 1024                 // padded row stride for P / H2 planes

#define NBINS 2048
#define HLO 0.3055f      // ln(1.5) - 0.10
#define HW_ 0.025f       // bin width
#define HINV 40.0f       // 1/HW_
#define HDELTA 0.10f     // selection margin (>= 2*|f32-f64| logit error)

// f64 weight arena offsets (in doubles)
#define W1OFF 0
#define B1OFF 270
#define P1OFF 280
#define W2OFF 290
#define B2OFF 1730
#define P2OFF 1746
#define W3OFF 1762
#define B3OFF 6370
#define P3OFF 6402
#define WAOFF 6434
#define BAOFF 6498
#define WBOFF 6500
#define BBOFF 6628
#define WDTOT 6632

// bijective XCD-aware row swizzle (m204): contiguous row band per XCD
__device__ __forceinline__ int xcd_swizzle(int bid, int nwg) {
    int q = nwg >> 3, r = nwg & 7;
    int x = bid & 7, i = bid >> 3;
    return (x < r ? x * (q + 1) : r * (q + 1) + (x - r) * q) + i;
}

// ---- prep: convert weights to f64; zero ctrl + hist ----
__global__ __launch_bounds__(256) void k_prep(
    const float* __restrict__ w1, const float* __restrict__ b1, const float* __restrict__ p1,
    const float* __restrict__ w2, const float* __restrict__ b2, const float* __restrict__ p2,
    const float* __restrict__ w3, const float* __restrict__ b3, const float* __restrict__ p3,
    const float* __restrict__ wa, const float* __restrict__ ba,
    const float* __restrict__ wb, const float* __restrict__ bb,
    double* __restrict__ wd, int* __restrict__ ctrl, u32* __restrict__ ghist)
{
    int t = threadIdx.x;
    if (t < 2) ctrl[t] = 0;
    for (int i = t; i < NBINS; i += 256) ghist[i] = 0u;
    for (int i = t; i < 270; i += 256)  wd[W1OFF + i] = (double)w1[i];
    if (t < 10) { wd[B1OFF + t] = (double)b1[t]; wd[P1OFF + t] = (double)p1[t]; }
    for (int i = t; i < 1440; i += 256) wd[W2OFF + i] = (double)w2[i];
    if (t < 16) { wd[B2OFF + t] = (double)b2[t]; wd[P2OFF + t] = (double)p2[t]; }
    for (int i = t; i < 4608; i += 256) wd[W3OFF + i] = (double)w3[i];
    if (t < 32) { wd[B3OFF + t] = (double)b3[t]; wd[P3OFF + t] = (double)p3[t]; }
    if (t < 64)  wd[WAOFF + t] = (double)wa[t];
    if (t < 2)   wd[BAOFF + t] = (double)ba[t];
    if (t < 128) wd[WBOFF + t] = (double)wb[t];
    if (t < 4)   wd[BBOFF + t] = (double)bb[t];
}

// ---------------- conv1 f32 (3->10) + bias + prelu + maxpool2, LDS-staged x ----------------
__global__ __launch_bounds__(256) void k_conv1f(
    const float* __restrict__ x, const float* __restrict__ w1,
    const float* __restrict__ b1, const float* __restrict__ p1,
    float* __restrict__ P)
{
    __shared__ float sw[270];
    __shared__ float sb[10], sp[10];
    __shared__ float xs[3][10][132];
    int tx = threadIdx.x, ty = threadIdx.y;
    int t = ty * 64 + tx;
    for (int i = t; i < 270; i += 256) sw[i] = w1[i];
    if (t < 10) { sb[t] = b1[t]; sp[t] = p1[t]; }
    int bx = blockIdx.x, by = blockIdx.y;
    const float4* x4 = (const float4*)x;
    for (int i = t; i < 990; i += 256) {
        int c = i / 330, rem = i % 330, r = rem / 33, k = rem % 33;
        int row = 8 * by + r; if (row > 2047) row = 2047;
        int col4 = bx * 32 + k; if (col4 > 511) col4 = 511;
        float4 v = x4[((size_t)c * 2048 + row) * 512 + col4];
        xs[c][r][k * 4 + 0] = v.x; xs[c][r][k * 4 + 1] = v.y;
        xs[c][r][k * 4 + 2] = v.z; xs[c][r][k * 4 + 3] = v.w;
    }
    __syncthreads();
    int px = bx * 64 + tx;
    int py = by * 4 + ty;
    if (px >= W1H || py >= W1H) return;
    float acc[10][4];
    #pragma unroll
    for (int ch = 0; ch < 10; ++ch) { acc[ch][0]=0.f; acc[ch][1]=0.f; acc[ch][2]=0.f; acc[ch][3]=0.f; }
    for (int c = 0; c < 3; ++c) {
        float in[4][4];
        #pragma unroll
        for (int u = 0; u < 4; ++u) {
            in[u][0] = xs[c][2*ty+u][2*tx+0];
            in[u][1] = xs[c][2*ty+u][2*tx+1];
            in[u][2] = xs[c][2*ty+u][2*tx+2];
            in[u][3] = xs[c][2*ty+u][2*tx+3];
        }
        #pragma unroll
        for (int ch = 0; ch < 10; ++ch) {
            const float* wp = sw + (ch * 3 + c) * 9;
            #pragma unroll
            for (int u = 0; u < 3; ++u)
                #pragma unroll
                for (int v = 0; v < 3; ++v) {
                    float w = wp[u * 3 + v];
                    acc[ch][0] = fmaf(in[u][v],         w, acc[ch][0]);
                    acc[ch][1] = fmaf(in[u][v + 1],     w, acc[ch][1]);
                    acc[ch][2] = fmaf(in[u + 1][v],     w, acc[ch][2]);
                    acc[ch][3] = fmaf(in[u + 1][v + 1], w, acc[ch][3]);
                }
        }
    }
    #pragma unroll
    for (int ch = 0; ch < 10; ++ch) {
        float m = fmaxf(fmaxf(acc[ch][0], acc[ch][1]), fmaxf(acc[ch][2], acc[ch][3])) + sb[ch];
        float r = m >= 0.f ? m : sp[ch] * m;
        P[((size_t)ch * W1H + py) * PSTR + px] = r;
    }
}

// helper macros for prefetched conv inner loops (8 och x 4 px per thread)
#define LOADF(A0, A1, src, cc, WH) { \
    _Pragma("unroll") \
    for (int u = 0; u < 3; ++u) { \
        const float* row_ = (src) + ((size_t)(cc) * (WH) + (size_t)(py + u)) * PSTR + gpx; \
        A0[u] = *(const float4*)(row_); \
        A1[u] = *(const float4*)(row_ + 4); \
    } }

#define FMABLK(A0, A1, cc, NOCH, SW) { \
    float fr[3][8]; \
    _Pragma("unroll") \
    for (int u = 0; u < 3; ++u) { \
        fr[u][0]=A0[u].x; fr[u][1]=A0[u].y; fr[u][2]=A0[u].z; fr[u][3]=A0[u].w; \
        fr[u][4]=A1[u].x; fr[u][5]=A1[u].y; fr[u][6]=A1[u].z; fr[u][7]=A1[u].w; \
    } \
    _Pragma("unroll") \
    for (int j = 0; j < 8; ++j) { \
        int o_ = och0 + j; \
        const float4* wv_ = (const float4*)((SW) + ((cc) * (NOCH) + o_) * 12); \
        float4 wA_ = wv_[0], wB_ = wv_[1], wC_ = wv_[2]; \
        float w_[9] = {wA_.x,wA_.y,wA_.z,wA_.w,wB_.x,wB_.y,wB_.z,wB_.w,wC_.x}; \
        _Pragma("unroll") \
        for (int u = 0; u < 3; ++u) \
            _Pragma("unroll") \
            for (int v = 0; v < 3; ++v) { \
                float wt_ = w_[u*3+v]; \
                _Pragma("unroll") \
                for (int p = 0; p < 4; ++p) \
                    acc[j][p] = fmaf(fr[u][p+v], wt_, acc[j][p]); \
            } \
    } }

// ------- conv2 f32 (10->16) + bias + prelu: 8och x 4px, 2-deep c-prefetch -------
// block (64,4): och0=(ty&1)*8, quarter=ty>>1; block covers 512px x 16och; grid (2, W2H swz)
__global__ __launch_bounds__(256, 4) void k_conv2f(
    const float* __restrict__ P, const float* __restrict__ w2,
    const float* __restrict__ b2, const float* __restrict__ p2,
    float* __restrict__ H2)
{
    __shared__ __align__(16) float sw[10 * 16 * 12]; // [c][o][12]
    __shared__ float sb[16], sp[16];
    int tx = threadIdx.x, ty = threadIdx.y;
    int t = ty * 64 + tx;
    for (int i = t; i < 1440; i += 256) {
        int o = i / 90, r = i % 90, c = r / 9, k = r % 9;
        sw[(c * 16 + o) * 12 + k] = w2[i];
    }
    if (t < 16) { sb[t] = b2[t]; sp[t] = p2[t]; }
    __syncthreads();
    int py = xcd_swizzle(blockIdx.y, W2H);
    int och0 = (ty & 1) * 8;
    int px_base = (ty >> 1) * 256 + tx * 4;
    int gpx = blockIdx.x * 512 + px_base;
    float acc[8][4];
    #pragma unroll
    for (int j = 0; j < 8; ++j) { acc[j][0]=0.f; acc[j][1]=0.f; acc[j][2]=0.f; acc[j][3]=0.f; }

    float4 a0[3], a1[3], b0[3], b1[3];
    LOADF(a0, a1, P, 0, W1H);
    #pragma unroll
    for (int c = 0; c < 10; c += 2) {
        LOADF(b0, b1, P, c + 1, W1H);
        FMABLK(a0, a1, c, 16, sw);
        if (c + 2 < 10) LOADF(a0, a1, P, c + 2, W1H);
        FMABLK(b0, b1, c + 1, 16, sw);
    }
    #pragma unroll
    for (int j = 0; j < 8; ++j) {
        int o = och0 + j;
        float bb_ = sb[o], pp_ = sp[o];
        #pragma unroll
        for (int p = 0; p < 4; ++p) {
            int px = gpx + p;
            if (px < W2H) {
                float v = acc[j][p] + bb_;
                v = v >= 0.f ? v : pp_ * v;
                H2[((size_t)o * W2H + py) * PSTR + px] = v;
            }
        }
    }
}

// ------- conv3 f32 (16->32) + prelu + cls head: 8och x 4px, 2-deep c-prefetch -------
// block (64,8): och0=(ty&3)*8, quarter=ty>>2; block covers 512px x 32och; grid (2, W3H swz)
__global__ __launch_bounds__(512, 4) void k_conv3f(
    const float* __restrict__ H2, const float* __restrict__ w3,
    const float* __restrict__ b3, const float* __restrict__ p3,
    const float* __restrict__ wa, const float* __restrict__ ba,
    float* __restrict__ Lg, u32* __restrict__ ghist)
{
    __shared__ __align__(16) float sw[16 * 32 * 12];   // 24576 B
    __shared__ float spart[4][512];                    // 8192 B
    __shared__ u32 hist[NBINS];                        // 8192 B
    __shared__ float sb[32], sp[32], swd[32];
    __shared__ float slgb;
    int tx = threadIdx.x, ty = threadIdx.y;
    int t = ty * 64 + tx;
    for (int i = t; i < 4608; i += 512) {
        int o = i / 144, rem = i % 144, c = rem / 9, k = rem % 9;
        sw[(c * 32 + o) * 12 + k] = w3[i];
    }
    if (t < 32) { sb[t] = b3[t]; sp[t] = p3[t]; swd[t] = wa[32 + t] - wa[t]; }
    if (t == 0) slgb = ba[1] - ba[0];
    for (int i = t; i < NBINS; i += 512) hist[i] = 0u;
    __syncthreads();

    int py = xcd_swizzle(blockIdx.y, W3H);
    int och0 = (ty & 3) * 8;
    int px_base = (ty >> 2) * 256 + tx * 4;
    int gpx = blockIdx.x * 512 + px_base;
    float acc[8][4];
    #pragma unroll
    for (int j = 0; j < 8; ++j) { acc[j][0]=0.f; acc[j][1]=0.f; acc[j][2]=0.f; acc[j][3]=0.f; }

    float4 a0[3], a1[3], b0[3], b1[3];
    LOADF(a0, a1, H2, 0, W2H);
    #pragma unroll
    for (int c = 0; c < 16; c += 2) {
        LOADF(b0, b1, H2, c + 1, W2H);
        FMABLK(a0, a1, c, 32, sw);
        if (c + 2 < 16) LOADF(a0, a1, H2, c + 2, W2H);
        FMABLK(b0, b1, c + 1, 32, sw);
    }

    // per-thread partial logit over its 8 channels
    float partv[4] = {0.f, 0.f, 0.f, 0.f};
    #pragma unroll
    for (int j = 0; j < 8; ++j) {
        int o = och0 + j;
        float bb_ = sb[o], pp_ = sp[o], wdd = swd[o];
        #pragma unroll
        for (int p = 0; p < 4; ++p) {
            float v = acc[j][p] + bb_;
            v = v >= 0.f ? v : pp_ * v;
            partv[p] = fmaf(wdd, v, partv[p]);
        }
    }
    #pragma unroll
    for (int p = 0; p < 4; ++p) spart[ty & 3][px_base + p] = partv[p];
    __syncthreads();

    // reduce 4 partials per pixel; thread t owns local px t
    {
        float lg = slgb + spart[0][t] + spart[1][t] + spart[2][t] + spart[3][t];
        int px = blockIdx.x * 512 + t;
        if (px < W3H) {
            Lg[(size_t)py * W3H + px] = lg;
            if (lg >= HLO) {
                int bin = (int)((lg - HLO) * HINV);
                if (bin > NBINS - 1) bin = NBINS - 1;
                atomicAdd(&hist[bin], 1u);
            }
        }
    }
    __syncthreads();
    for (int i = t; i < NBINS; i += 512) {
        u32 v = hist[i];
        if (v) atomicAdd(&ghist[i], v);
    }
}

// ---- select (with fused threshold scan): pixels with f32 logit >= Tsel ----
__global__ __launch_bounds__(256) void k_select(
    const float* __restrict__ Lg, const u32* __restrict__ ghist,
    int* __restrict__ ctrl, u32* __restrict__ selidx)
{
    __shared__ u32 h[NBINS];
    __shared__ u32 tsum[256];
    __shared__ int best;
    __shared__ float sT;
    int t = threadIdx.x;
    for (int i = t; i < NBINS; i += 256) h[i] = ghist[i];
    if (t == 0) best = -1;
    __syncthreads();
    u32 s = 0;
    #pragma unroll
    for (int k = 0; k < 8; ++k) s += h[t * 8 + k];
    tsum[t] = s;
    __syncthreads();
    for (int off = 1; off < 256; off <<= 1) {
        u32 add = (t + off < 256) ? tsum[t + off] : 0u;
        __syncthreads();
        tsum[t] += add;
        __syncthreads();
    }
    u32 cum = (t < 255) ? tsum[t + 1] : 0u;
    int cand = -1;
    for (int k = 7; k >= 0; --k) {
        cum += h[t * 8 + k];
        if (cand < 0 && cum >= 512) cand = t * 8 + k;
    }
    if (cand >= 0) atomicMax(&best, cand);
    __syncthreads();
    if (t == 0) sT = (best < 0) ? HLO : (HLO + (float)best * HW_ - HDELTA);
    __syncthreads();
    float T = sT;
    int stride = gridDim.x * 256;
    for (int i = blockIdx.x * 256 + t; i < NPIX; i += stride) {
        if (Lg[i] >= T) {
            int slot = atomicAdd(&ctrl[0], 1);
            selidx[slot] = (u32)i;
        }
    }
}

// ---- recompute: exact f64 pyramid per selected pixel; emit key + boxes ----
__global__ __launch_bounds__(64) void k_recomp(
    const float* __restrict__ x, const double* __restrict__ wd,
    const u32* __restrict__ selidx, int* __restrict__ ctrl,
    u64* __restrict__ keys, double* __restrict__ boxplane)
{
    __shared__ double xw[3][12][12];
    __shared__ double Pw[10][5][5];
    __shared__ double Hw[16][3][3];
    __shared__ double vch[32];
    int nsel = ctrl[0]; if (nsel > NPIX) nsel = NPIX;
    int t = threadIdx.x;
    for (int s = blockIdx.x; s < nsel; s += gridDim.x) {
        u32 idx = selidx[s];
        int y3 = (int)(idx / W3H), x3 = (int)(idx % W3H);
        int xr = 2 * y3, xc = 2 * x3;
        for (int i = t; i < 432; i += 64) {
            int c = i / 144, r = (i % 144) / 12, cc = i % 12;
            xw[c][r][cc] = (double)x[((size_t)c * 2048 + (xr + r)) * 2048 + (xc + cc)];
        }
        __syncthreads();
        for (int i = t; i < 250; i += 64) {
            int ch = i / 25, py = (i % 25) / 5, px = i % 5;
            int r0 = py * 2, c0 = px * 2;
            double a00=0.0, a01=0.0, a10=0.0, a11=0.0;
            for (int c = 0; c < 3; ++c) {
                const double* wp = wd + W1OFF + (ch * 3 + c) * 9;
                #pragma unroll
                for (int u = 0; u < 3; ++u)
                    #pragma unroll
                    for (int v = 0; v < 3; ++v) {
                        double w = wp[u * 3 + v];
                        a00 = fma(xw[c][r0+u][c0+v],     w, a00);
                        a01 = fma(xw[c][r0+u][c0+v+1],   w, a01);
                        a10 = fma(xw[c][r0+u+1][c0+v],   w, a10);
                        a11 = fma(xw[c][r0+u+1][c0+v+1], w, a11);
                    }
            }
            double m = fmax(fmax(a00, a01), fmax(a10, a11)) + wd[B1OFF + ch];
            Pw[ch][py][px] = m >= 0.0 ? m : wd[P1OFF + ch] * m;
        }
        __syncthreads();
        for (int i = t; i < 144; i += 64) {
            int o = i / 9, hy = (i % 9) / 3, hx = i % 3;
            double acc = 0.0;
            for (int c = 0; c < 10; ++c) {
                const double* wp = wd + W2OFF + (o * 10 + c) * 9;
                #pragma unroll
                for (int k = 0; k < 9; ++k)
                    acc = fma(Pw[c][hy + k / 3][hx + k % 3], wp[k], acc);
            }
            acc += wd[B2OFF + o];
            Hw[o][hy][hx] = acc >= 0.0 ? acc : wd[P2OFF + o] * acc;
        }
        __syncthreads();
        if (t < 32) {
            double acc = 0.0;
            for (int c = 0; c < 16; ++c) {
                const double* wp = wd + W3OFF + (t * 16 + c) * 9;
                #pragma unroll
                for (int k = 0; k < 9; ++k)
                    acc = fma(Hw[c][k / 3][k % 3], wp[k], acc);
            }
            acc += wd[B3OFF + t];
            vch[t] = acc >= 0.0 ? acc : wd[P3OFF + t] * acc;
        }
        __syncthreads();
        if (t == 0) {
            double c0 = wd[BAOFF + 0], c1 = wd[BAOFF + 1];
            for (int o = 0; o < 32; ++o) {
                c0 = fma(wd[WAOFF + o], vch[o], c0);
                c1 = fma(wd[WAOFF + 32 + o], vch[o], c1);
            }
            double mx = fmax(c0, c1);
            double e0 = exp(c0 - mx), e1 = exp(c1 - mx);
            double prob = e1 / (e0 + e1);
            if (prob >= 0.6) {
                double r0 = wd[BBOFF+0], r1 = wd[BBOFF+1], r2 = wd[BBOFF+2], r3 = wd[BBOFF+3];
                for (int o = 0; o < 32; ++o) {
                    double v = vch[o];
                    r0 = fma(wd[WBOFF + o], v, r0);
                    r1 = fma(wd[WBOFF + 32 + o], v, r1);
                    r2 = fma(wd[WBOFF + 64 + o], v, r2);
                    r3 = fma(wd[WBOFF + 96 + o], v, r3);
                }
                double fx = (double)x3, fy = (double)y3;
                double cx = (fx * 2.0 + 6.0) / 0.6;
                double cy = (fy * 2.0 + 6.0) / 0.6;
                double ww = 12.0 / 0.6, hw = ww / 2.0;
                double* bp = boxplane + (size_t)idx * 5;
                bp[0] = cx - hw + r0 * ww;
                bp[1] = cy - hw + r1 * ww;
                bp[2] = cx + hw + r2 * ww;
                bp[3] = cy + hw + r3 * ww;
                bp[4] = prob;
                u64 bits = (u64)__double_as_longlong(prob);
                u64 kh = (bits - 0x3FE0000000000000ull) >> 9;
                int slot = atomicAdd(&ctrl[1], 1);
                keys[slot] = (kh << 20) | ((u64)(~idx) & IDXMASK);
            }
        }
        __syncthreads();
    }
}

// ------- pass B: each block sorts 4 chunks of 512, keeps local top-512 (desc) -------
__global__ __launch_bounds__(512) void k_sortchunks(
    const u64* __restrict__ cand, const int* __restrict__ ctrl,
    u64* __restrict__ sorted)
{
    __shared__ u64 stop_[512];
    __shared__ u64 schunk[512];
    int tid = threadIdx.x;
    int n = ctrl[1]; if (n > NPIX) n = NPIX;
    long base0 = (long)blockIdx.x * 2048;
    stop_[tid] = 0ull;
    if (base0 < n) {
        for (int s = 0; s < 4; ++s) {
            long base = base0 + (long)s * 512;
            if (base >= n) break;
            schunk[tid] = (base + tid < n) ? cand[base + tid] : 0ull;
            for (int k = 2; k <= 512; k <<= 1)
                for (int j = k >> 1; j > 0; j >>= 1) {
                    __syncthreads();
                    int ixj = tid ^ j;
                    if (ixj > tid) {
                        u64 a = schunk[tid], b = schunk[ixj];
                        bool desc = ((tid & k) == 0);
                        if (desc ? (a < b) : (a > b)) { schunk[tid] = b; schunk[ixj] = a; }
                    }
                }
            __syncthreads();
            u64 m = stop_[tid], v = schunk[511 - tid];
            stop_[tid] = m > v ? m : v;
            for (int j = 256; j > 0; j >>= 1) {
                __syncthreads();
                int ixj = tid ^ j;
                if (ixj > tid) {
                    u64 a = stop_[tid], b = stop_[ixj];
                    if (a < b) { stop_[tid] = b; stop_[ixj] = a; }
                }
            }
            __syncthreads();
        }
    }
    sorted[(size_t)blockIdx.x * 512 + tid] = stop_[tid];
}

// ------- merge 8 consecutive sorted-512 lists -> one sorted-512 -------
__global__ __launch_bounds__(512) void k_merge8(
    const u64* __restrict__ in, u64* __restrict__ out, int nin)
{
    __shared__ u64 s[512];
    int tid = threadIdx.x;
    int base = blockIdx.x * 8;
    s[tid] = (base < nin) ? in[(size_t)base * 512 + tid] : 0ull;
    for (int c = 1; c < 8; ++c) {
        int li = base + c;
        u64 v = (li < nin) ? in[(size_t)li * 512 + (511 - tid)] : 0ull;
        __syncthreads();
        u64 m = s[tid];
        s[tid] = m > v ? m : v;
        for (int j = 256; j > 0; j >>= 1) {
            __syncthreads();
            int ixj = tid ^ j;
            if (ixj > tid) {
                u64 a = s[tid], b = s[ixj];
                if (a < b) { s[tid] = b; s[ixj] = a; }
            }
        }
        __syncthreads();
    }
    out[(size_t)blockIdx.x * 512 + tid] = s[tid];
}

// ------- boxmat: parallel build of both suppression bit-matrices + box SoA -------
__global__ __launch_bounds__(512) void k_boxmat(
    const u64* __restrict__ lists, const double* __restrict__ boxplane,
    u64* __restrict__ mats, double* __restrict__ bxs, u64* __restrict__ validw)
{
    __shared__ double sx1[512], sy1[512], sx2[512], sy2[512], sar[512];
    int tid = threadIdx.x;
    u64 key = lists[tid];
    bool valid = key != 0ull;
    double x1 = 0.0, y1 = 0.0, x2 = 0.0, y2 = 0.0, score = 0.0;
    if (valid) {
        u32 idx = (u32)(IDXMASK - (key & IDXMASK));
        const double* bp = boxplane + (size_t)idx * 5;
        x1 = bp[0]; y1 = bp[1]; x2 = bp[2]; y2 = bp[3]; score = bp[4];
    }
    double area = (x2 - x1) * (y2 - y1);
    sx1[tid] = x1; sy1[tid] = y1; sx2[tid] = x2; sy2[tid] = y2; sar[tid] = area;
    if (blockIdx.x == 0 && blockIdx.y == 0) {
        bxs[tid] = x1; bxs[512 + tid] = y1; bxs[1024 + tid] = x2;
        bxs[1536 + tid] = y2; bxs[2048 + tid] = score;
        u64 bal = __ballot(valid);
        if ((tid & 63) == 0) validw[tid >> 6] = bal;
    }
    __syncthreads();
    double thr = (blockIdx.y == 0) ? 0.5 : 0.7;
    int wv = tid >> 6;
    int rowbase = blockIdx.x * 64;
    for (int r = 0; r < 64; ++r) {
        int i = rowbase + r;
        double ix1 = fmax(sx1[i], x1);
        double iy1 = fmax(sy1[i], y1);
        double ix2 = fmin(sx2[i], x2);
        double iy2 = fmin(sy2[i], y2);
        double inter = fmax(ix2 - ix1, 0.0) * fmax(iy2 - iy1, 0.0);
        double uni = sar[i] + area - inter + 1e-9;
        bool sup = (uni > 0.0) && (inter > thr * uni) && (tid > i);
        u64 w = __ballot(sup);
        if ((tid & 63) == 0)
            mats[((size_t)blockIdx.y * 512 + i) * 8 + wv] = w;
    }
}

// ------- nmsfin: two serial greedy scans over precomputed matrices; output -------
__global__ __launch_bounds__(512) void k_nmsfin(
    const u64* __restrict__ mats, const double* __restrict__ bxs,
    const u64* __restrict__ validw, float* __restrict__ out)
{
    __shared__ u64 keepw[8];
    int tid = threadIdx.x;
    if (tid < 8) keepw[tid] = validw[tid];
    __syncthreads();
    for (int pass = 0; pass < 2; ++pass) {
        if (tid < 64) {
            const u64* mat = mats + (size_t)pass * 512 * 8;
            u64 kw = (tid < 8) ? keepw[tid] : 0ull;
            for (int i = 0; i < 512; ++i) {
                u64 row = mat[i * 8 + (tid & 7)];
                u64 cur = __shfl(kw, i >> 6);
                if ((cur >> (i & 63)) & 1) kw &= ~row;
            }
            if (tid < 8) keepw[tid] = kw;
        }
        __syncthreads();
    }
    double kf = ((keepw[tid >> 6] >> (tid & 63)) & 1) ? 1.0 : 0.0;
    out[tid * 5 + 0] = (float)(bxs[tid] * kf);
    out[tid * 5 + 1] = (float)(bxs[512 + tid] * kf);
    out[tid * 5 + 2] = (float)(bxs[1024 + tid] * kf);
    out[tid * 5 + 3] = (float)(bxs[1536 + tid] * kf);
    out[tid * 5 + 4] = (float)(bxs[2048 + tid] * kf);
}

extern "C" void kernel_launch(void* const* d_in, const int* in_sizes, int n_in,
                              void* d_out, int out_size, void* d_ws, size_t ws_size,
                              hipStream_t stream)
{
    const float* x  = (const float*)d_in[0];
    const float* w1 = (const float*)d_in[1];
    const float* b1 = (const float*)d_in[2];
    const float* p1 = (const float*)d_in[3];
    const float* w2 = (const float*)d_in[4];
    const float* b2 = (const float*)d_in[5];
    const float* p2 = (const float*)d_in[6];
    const float* w3 = (const float*)d_in[7];
    const float* b3 = (const float*)d_in[8];
    const float* p3 = (const float*)d_in[9];
    const float* wa = (const float*)d_in[10];
    const float* ba = (const float*)d_in[11];
    const float* wb = (const float*)d_in[12];
    const float* bb = (const float*)d_in[13];
    float* out = (float*)d_out;

    char* ws = (char*)d_ws;
    float*  Pf    = (float*) (ws);                       // 10*1023*1024*4 = 41,902,080
    float*  H2f   = (float*) (ws + 41902080);            // 16*1021*1024*4 = 66,912,256
    float*  Lg    = (float*) (ws + 108814336);           // NPIX*4 -> 4,153,600
    u32*    ghist = (u32*)   (ws + 112967936);           // 8192
    int*    ctrl  = (int*)   (ws + 112976128);           // 256: [0]=selcnt [1]=emit
    u32*    selidx= (u32*)   (ws + 112976384);           // NPIX*4 -> 4,153,600
    u64*    keys  = (u64*)   (ws + 117129984);           // NPIX*8 -> 8,307,200
    u64*    sorted= (u64*)   (ws + 125437184);           // 508*512*8 = 2,080,768
    u64*    l1out = (u64*)   (ws + 127517952);           // 64*512*8 = 262,144
    u64*    l2out = (u64*)   (ws + 127780096);           // 8*512*8 = 32,768
    double* boxpl = (double*)(ws + 127812864);           // NPIX*5*8 -> 41,534,720
    double* wd    = (double*)(ws + 169347584);           // WDTOT*8 = 53,056
    u64*    l3out = (u64*)   (ws + 125437184);           // aliases sorted (free by then)
    u64*    mats  = (u64*)   (ws + 125441280);           // 2*512*8*8 = 65,536
    double* bxs   = (double*)(ws + 125506816);           // 5*512*8 = 20,480
    u64*    vwords= (u64*)   (ws + 125527296);           // 64

    k_prep<<<1, 256, 0, stream>>>(w1, b1, p1, w2, b2, p2, w3, b3, p3, wa, ba, wb, bb, wd, ctrl, ghist);
    k_conv1f<<<dim3(16, 256), dim3(64, 4), 0, stream>>>(x, w1, b1, p1, Pf);
    k_conv2f<<<dim3(2, W2H), dim3(64, 4), 0, stream>>>(Pf, w2, b2, p2, H2f);
    k_conv3f<<<dim3(2, W3H), dim3(64, 8), 0, stream>>>(H2f, w3, b3, p3, wa, ba, Lg, ghist);
    k_select<<<1024, 256, 0, stream>>>(Lg, ghist, ctrl, selidx);
    k_recomp<<<2048, 64, 0, stream>>>(x, wd, selidx, ctrl, keys, boxpl);
    k_sortchunks<<<508, 512, 0, stream>>>(keys, ctrl, sorted);
    k_merge8<<<64, 512, 0, stream>>>(sorted, l1out, 508);
    k_merge8<<<8, 512, 0, stream>>>(l1out, l2out, 64);
    k_merge8<<<1, 512, 0, stream>>>(l2out, l3out, 8);
    k_boxmat<<<dim3(8, 2), 512, 0, stream>>>(l3out, boxpl, mats, bxs, vwords);
    k_nmsfin<<<1, 512, 0, stream>>>(mats, bxs, vwords, out);
}

// Round 11
// 584.073 us; speedup vs baseline: 4.8166x; 4.8166x over previous
//
#include <hip/hip_runtime.h>

typedef unsigned long long u64;
typedef unsigned int u32;

#define W1H 1023   // after conv1+pool
#define W2H 1021   // after conv2
#define W3H 1019   // after conv3
#define NPIX (W3H * W3H)          // 1,038,361 < 2^20
#define IDXMASK 0xFFFFFull
#define PSTR 1024                 // padded row stride for P / H2 planes

#define NBINS 2048
#define HLO 0.3055f      // ln(1.5) - 0.10
#define HW_ 0.025f       // bin width
#define HINV 40.0f       // 1/HW_
#define HDELTA 0.10f     // selection margin (>= 2*|f32-f64| logit error)

// f64 weight arena offsets (in doubles)
#define W1OFF 0
#define B1OFF 270
#define P1OFF 280
#define W2OFF 290
#define B2OFF 1730
#define P2OFF 1746
#define W3OFF 1762
#define B3OFF 6370
#define P3OFF 6402
#define WAOFF 6434
#define BAOFF 6498
#define WBOFF 6500
#define BBOFF 6628
#define WDTOT 6632

// bijective XCD-aware row swizzle (m204): contiguous row band per XCD
__device__ __forceinline__ int xcd_swizzle(int bid, int nwg) {
    int q = nwg >> 3, r = nwg & 7;
    int x = bid & 7, i = bid >> 3;
    return (x < r ? x * (q + 1) : r * (q + 1) + (x - r) * q) + i;
}

// ---- prep: convert weights to f64; zero ctrl + hist ----
__global__ __launch_bounds__(256) void k_prep(
    const float* __restrict__ w1, const float* __restrict__ b1, const float* __restrict__ p1,
    const float* __restrict__ w2, const float* __restrict__ b2, const float* __restrict__ p2,
    const float* __restrict__ w3, const float* __restrict__ b3, const float* __restrict__ p3,
    const float* __restrict__ wa, const float* __restrict__ ba,
    const float* __restrict__ wb, const float* __restrict__ bb,
    double* __restrict__ wd, int* __restrict__ ctrl, u32* __restrict__ ghist)
{
    int t = threadIdx.x;
    if (t < 2) ctrl[t] = 0;
    for (int i = t; i < NBINS; i += 256) ghist[i] = 0u;
    for (int i = t; i < 270; i += 256)  wd[W1OFF + i] = (double)w1[i];
    if (t < 10) { wd[B1OFF + t] = (double)b1[t]; wd[P1OFF + t] = (double)p1[t]; }
    for (int i = t; i < 1440; i += 256) wd[W2OFF + i] = (double)w2[i];
    if (t < 16) { wd[B2OFF + t] = (double)b2[t]; wd[P2OFF + t] = (double)p2[t]; }
    for (int i = t; i < 4608; i += 256) wd[W3OFF + i] = (double)w3[i];
    if (t < 32) { wd[B3OFF + t] = (double)b3[t]; wd[P3OFF + t] = (double)p3[t]; }
    if (t < 64)  wd[WAOFF + t] = (double)wa[t];
    if (t < 2)   wd[BAOFF + t] = (double)ba[t];
    if (t < 128) wd[WBOFF + t] = (double)wb[t];
    if (t < 4)   wd[BBOFF + t] = (double)bb[t];
}

// ---------------- conv1 f32 (3->10) + bias + prelu + maxpool2, LDS-staged x ----------------
__global__ __launch_bounds__(256) void k_conv1f(
    const float* __restrict__ x, const float* __restrict__ w1,
    const float* __restrict__ b1, const float* __restrict__ p1,
    float* __restrict__ P)
{
    __shared__ float sw[270];
    __shared__ float sb[10], sp[10];
    __shared__ float xs[3][10][132];
    int tx = threadIdx.x, ty = threadIdx.y;
    int t = ty * 64 + tx;
    for (int i = t; i < 270; i += 256) sw[i] = w1[i];
    if (t < 10) { sb[t] = b1[t]; sp[t] = p1[t]; }
    int bx = blockIdx.x, by = blockIdx.y;
    const float4* x4 = (const float4*)x;
    for (int i = t; i < 990; i += 256) {
        int c = i / 330, rem = i % 330, r = rem / 33, k = rem % 33;
        int row = 8 * by + r; if (row > 2047) row = 2047;
        int col4 = bx * 32 + k; if (col4 > 511) col4 = 511;
        float4 v = x4[((size_t)c * 2048 + row) * 512 + col4];
        xs[c][r][k * 4 + 0] = v.x; xs[c][r][k * 4 + 1] = v.y;
        xs[c][r][k * 4 + 2] = v.z; xs[c][r][k * 4 + 3] = v.w;
    }
    __syncthreads();
    int px = bx * 64 + tx;
    int py = by * 4 + ty;
    if (px >= W1H || py >= W1H) return;
    float acc[10][4];
    #pragma unroll
    for (int ch = 0; ch < 10; ++ch) { acc[ch][0]=0.f; acc[ch][1]=0.f; acc[ch][2]=0.f; acc[ch][3]=0.f; }
    for (int c = 0; c < 3; ++c) {
        float in[4][4];
        #pragma unroll
        for (int u = 0; u < 4; ++u) {
            in[u][0] = xs[c][2*ty+u][2*tx+0];
            in[u][1] = xs[c][2*ty+u][2*tx+1];
            in[u][2] = xs[c][2*ty+u][2*tx+2];
            in[u][3] = xs[c][2*ty+u][2*tx+3];
        }
        #pragma unroll
        for (int ch = 0; ch < 10; ++ch) {
            const float* wp = sw + (ch * 3 + c) * 9;
            #pragma unroll
            for (int u = 0; u < 3; ++u)
                #pragma unroll
                for (int v = 0; v < 3; ++v) {
                    float w = wp[u * 3 + v];
                    acc[ch][0] = fmaf(in[u][v],         w, acc[ch][0]);
                    acc[ch][1] = fmaf(in[u][v + 1],     w, acc[ch][1]);
                    acc[ch][2] = fmaf(in[u + 1][v],     w, acc[ch][2]);
                    acc[ch][3] = fmaf(in[u + 1][v + 1], w, acc[ch][3]);
                }
        }
    }
    #pragma unroll
    for (int ch = 0; ch < 10; ++ch) {
        float m = fmaxf(fmaxf(acc[ch][0], acc[ch][1]), fmaxf(acc[ch][2], acc[ch][3])) + sb[ch];
        float r = m >= 0.f ? m : sp[ch] * m;
        P[((size_t)ch * W1H + py) * PSTR + px] = r;
    }
}

// ------- conv2 f32 (10->16) + bias + prelu: 8px x 8och per thread -------
// block (64,4): ty&1 = och group (x8), ty>>1 = px half (x512); block covers 1024px x 16och
__global__ __launch_bounds__(256) void k_conv2f(
    const float* __restrict__ P, const float* __restrict__ w2,
    const float* __restrict__ b2, const float* __restrict__ p2,
    float* __restrict__ H2)
{
    __shared__ __align__(16) float sw[10 * 16 * 12]; // [c][o][12] f4-padded
    __shared__ float sb[16], sp[16];
    int tx = threadIdx.x, ty = threadIdx.y;
    int t = ty * 64 + tx;
    for (int i = t; i < 1440; i += 256) {
        int o = i / 90, r = i % 90, c = r / 9, k = r % 9;
        sw[(c * 16 + o) * 12 + k] = w2[i];
    }
    if (t < 16) { sb[t] = b2[t]; sp[t] = p2[t]; }
    __syncthreads();
    int py = xcd_swizzle(blockIdx.y, W2H);
    int och0 = (ty & 1) * 8;
    int px_base = (ty >> 1) * 512 + tx * 8;
    float acc[8][8];
    #pragma unroll
    for (int j = 0; j < 8; ++j)
        #pragma unroll
        for (int p = 0; p < 8; ++p) acc[j][p] = 0.f;

    for (int c = 0; c < 10; ++c) {
        float f[3][12];
        #pragma unroll
        for (int u = 0; u < 3; ++u) {
            const float* row = P + ((size_t)c * W1H + (py + u)) * PSTR + px_base;
            float4 a = *(const float4*)(row);
            float4 b = *(const float4*)(row + 4);
            float4 d = *(const float4*)(row + 8);
            f[u][0]=a.x; f[u][1]=a.y; f[u][2]=a.z;  f[u][3]=a.w;
            f[u][4]=b.x; f[u][5]=b.y; f[u][6]=b.z;  f[u][7]=b.w;
            f[u][8]=d.x; f[u][9]=d.y; f[u][10]=d.z; f[u][11]=d.w;
        }
        #pragma unroll
        for (int j = 0; j < 8; ++j) {
            int o = och0 + j;
            const float4* wv = (const float4*)(sw + (c * 16 + o) * 12);
            float4 wA = wv[0], wB = wv[1], wC = wv[2];
            float w[9] = {wA.x,wA.y,wA.z,wA.w,wB.x,wB.y,wB.z,wB.w,wC.x};
            #pragma unroll
            for (int u = 0; u < 3; ++u)
                #pragma unroll
                for (int v = 0; v < 3; ++v) {
                    float wt = w[u*3+v];
                    #pragma unroll
                    for (int p = 0; p < 8; ++p)
                        acc[j][p] = fmaf(f[u][p+v], wt, acc[j][p]);
                }
        }
    }
    #pragma unroll
    for (int j = 0; j < 8; ++j) {
        int o = och0 + j;
        float bb_ = sb[o], pp_ = sp[o];
        #pragma unroll
        for (int p = 0; p < 8; ++p) {
            int px = px_base + p;
            if (px < W2H) {
                float v = acc[j][p] + bb_;
                v = v >= 0.f ? v : pp_ * v;
                H2[((size_t)o * W2H + py) * PSTR + px] = v;
            }
        }
    }
}

// ------- conv3 f32 (16->32) + prelu + cls head: 8px x 8och per thread -------
// block (64,8): ty&3 = och group (x8), ty>>2 = px half (x512); block covers 1024px x 32och
__global__ __launch_bounds__(512, 2) void k_conv3f(
    const float* __restrict__ H2, const float* __restrict__ w3,
    const float* __restrict__ b3, const float* __restrict__ p3,
    const float* __restrict__ wa, const float* __restrict__ ba,
    float* __restrict__ Lg, u32* __restrict__ ghist)
{
    __shared__ __align__(16) float sw[16 * 32 * 12];   // 24576 B
    __shared__ float spart[4][1024];                   // 16384 B
    __shared__ u32 hist[NBINS];                        // 8192 B
    __shared__ float sb[32], sp[32], swd[32];
    __shared__ float slgb;
    int tx = threadIdx.x, ty = threadIdx.y;
    int t = ty * 64 + tx;
    for (int i = t; i < 4608; i += 512) {
        int o = i / 144, rem = i % 144, c = rem / 9, k = rem % 9;
        sw[(c * 32 + o) * 12 + k] = w3[i];
    }
    if (t < 32) { sb[t] = b3[t]; sp[t] = p3[t]; swd[t] = wa[32 + t] - wa[t]; }
    if (t == 0) slgb = ba[1] - ba[0];
    for (int i = t; i < NBINS; i += 512) hist[i] = 0u;
    __syncthreads();

    int py = xcd_swizzle(blockIdx.y, W3H);
    int och0 = (ty & 3) * 8;
    int px_base = (ty >> 2) * 512 + tx * 8;
    float acc[8][8];
    #pragma unroll
    for (int j = 0; j < 8; ++j)
        #pragma unroll
        for (int p = 0; p < 8; ++p) acc[j][p] = 0.f;

    for (int c = 0; c < 16; ++c) {
        float f[3][12];
        #pragma unroll
        for (int u = 0; u < 3; ++u) {
            const float* row = H2 + ((size_t)c * W2H + (py + u)) * PSTR + px_base;
            float4 a = *(const float4*)(row);
            float4 b = *(const float4*)(row + 4);
            float4 d = *(const float4*)(row + 8);
            f[u][0]=a.x; f[u][1]=a.y; f[u][2]=a.z;  f[u][3]=a.w;
            f[u][4]=b.x; f[u][5]=b.y; f[u][6]=b.z;  f[u][7]=b.w;
            f[u][8]=d.x; f[u][9]=d.y; f[u][10]=d.z; f[u][11]=d.w;
        }
        #pragma unroll
        for (int j = 0; j < 8; ++j) {
            int o = och0 + j;
            const float4* wv = (const float4*)(sw + (c * 32 + o) * 12);
            float4 wA = wv[0], wB = wv[1], wC = wv[2];
            float w[9] = {wA.x,wA.y,wA.z,wA.w,wB.x,wB.y,wB.z,wB.w,wC.x};
            #pragma unroll
            for (int u = 0; u < 3; ++u)
                #pragma unroll
                for (int v = 0; v < 3; ++v) {
                    float wt = w[u*3+v];
                    #pragma unroll
                    for (int p = 0; p < 8; ++p)
                        acc[j][p] = fmaf(f[u][p+v], wt, acc[j][p]);
                }
        }
    }

    // per-thread partial logit over its 8 channels
    float partv[8];
    #pragma unroll
    for (int p = 0; p < 8; ++p) partv[p] = 0.f;
    #pragma unroll
    for (int j = 0; j < 8; ++j) {
        int o = och0 + j;
        float bb_ = sb[o], pp_ = sp[o], wdd = swd[o];
        #pragma unroll
        for (int p = 0; p < 8; ++p) {
            float v = acc[j][p] + bb_;
            v = v >= 0.f ? v : pp_ * v;
            partv[p] = fmaf(wdd, v, partv[p]);
        }
    }
    #pragma unroll
    for (int p = 0; p < 8; ++p) spart[ty & 3][px_base + p] = partv[p];
    __syncthreads();

    // reduce 4 partials per pixel; thread t owns px t and t+512
    #pragma unroll
    for (int rep = 0; rep < 2; ++rep) {
        int pl = t + rep * 512;
        float lg = slgb;
        #pragma unroll
        for (int g = 0; g < 4; ++g) lg += spart[g][pl];
        if (pl < W3H) {
            Lg[(size_t)py * W3H + pl] = lg;
            if (lg >= HLO) {
                int bin = (int)((lg - HLO) * HINV);
                if (bin > NBINS - 1) bin = NBINS - 1;
                atomicAdd(&hist[bin], 1u);
            }
        }
    }
    __syncthreads();
    for (int i = t; i < NBINS; i += 512) {
        u32 v = hist[i];
        if (v) atomicAdd(&ghist[i], v);
    }
}

// ---- select (with fused threshold scan): pixels with f32 logit >= Tsel ----
__global__ __launch_bounds__(256) void k_select(
    const float* __restrict__ Lg, const u32* __restrict__ ghist,
    int* __restrict__ ctrl, u32* __restrict__ selidx)
{
    __shared__ u32 h[NBINS];
    __shared__ u32 tsum[256];
    __shared__ int best;
    __shared__ float sT;
    int t = threadIdx.x;
    for (int i = t; i < NBINS; i += 256) h[i] = ghist[i];
    if (t == 0) best = -1;
    __syncthreads();
    u32 s = 0;
    #pragma unroll
    for (int k = 0; k < 8; ++k) s += h[t * 8 + k];
    tsum[t] = s;
    __syncthreads();
    for (int off = 1; off < 256; off <<= 1) {
        u32 add = (t + off < 256) ? tsum[t + off] : 0u;
        __syncthreads();
        tsum[t] += add;
        __syncthreads();
    }
    u32 cum = (t < 255) ? tsum[t + 1] : 0u;
    int cand = -1;
    for (int k = 7; k >= 0; --k) {
        cum += h[t * 8 + k];
        if (cand < 0 && cum >= 512) cand = t * 8 + k;
    }
    if (cand >= 0) atomicMax(&best, cand);
    __syncthreads();
    if (t == 0) sT = (best < 0) ? HLO : (HLO + (float)best * HW_ - HDELTA);
    __syncthreads();
    float T = sT;
    int stride = gridDim.x * 256;
    for (int i = blockIdx.x * 256 + t; i < NPIX; i += stride) {
        if (Lg[i] >= T) {
            int slot = atomicAdd(&ctrl[0], 1);
            selidx[slot] = (u32)i;
        }
    }
}

// ---- recompute: exact f64 pyramid per selected pixel; emit key + boxes ----
__global__ __launch_bounds__(64) void k_recomp(
    const float* __restrict__ x, const double* __restrict__ wd,
    const u32* __restrict__ selidx, int* __restrict__ ctrl,
    u64* __restrict__ keys, double* __restrict__ boxplane)
{
    __shared__ double xw[3][12][12];
    __shared__ double Pw[10][5][5];
    __shared__ double Hw[16][3][3];
    __shared__ double vch[32];
    int nsel = ctrl[0]; if (nsel > NPIX) nsel = NPIX;
    int t = threadIdx.x;
    for (int s = blockIdx.x; s < nsel; s += gridDim.x) {
        u32 idx = selidx[s];
        int y3 = (int)(idx / W3H), x3 = (int)(idx % W3H);
        int xr = 2 * y3, xc = 2 * x3;
        for (int i = t; i < 432; i += 64) {
            int c = i / 144, r = (i % 144) / 12, cc = i % 12;
            xw[c][r][cc] = (double)x[((size_t)c * 2048 + (xr + r)) * 2048 + (xc + cc)];
        }
        __syncthreads();
        for (int i = t; i < 250; i += 64) {
            int ch = i / 25, py = (i % 25) / 5, px = i % 5;
            int r0 = py * 2, c0 = px * 2;
            double a00=0.0, a01=0.0, a10=0.0, a11=0.0;
            for (int c = 0; c < 3; ++c) {
                const double* wp = wd + W1OFF + (ch * 3 + c) * 9;
                #pragma unroll
                for (int u = 0; u < 3; ++u)
                    #pragma unroll
                    for (int v = 0; v < 3; ++v) {
                        double w = wp[u * 3 + v];
                        a00 = fma(xw[c][r0+u][c0+v],     w, a00);
                        a01 = fma(xw[c][r0+u][c0+v+1],   w, a01);
                        a10 = fma(xw[c][r0+u+1][c0+v],   w, a10);
                        a11 = fma(xw[c][r0+u+1][c0+v+1], w, a11);
                    }
            }
            double m = fmax(fmax(a00, a01), fmax(a10, a11)) + wd[B1OFF + ch];
            Pw[ch][py][px] = m >= 0.0 ? m : wd[P1OFF + ch] * m;
        }
        __syncthreads();
        for (int i = t; i < 144; i += 64) {
            int o = i / 9, hy = (i % 9) / 3, hx = i % 3;
            double acc = 0.0;
            for (int c = 0; c < 10; ++c) {
                const double* wp = wd + W2OFF + (o * 10 + c) * 9;
                #pragma unroll
                for (int k = 0; k < 9; ++k)
                    acc = fma(Pw[c][hy + k / 3][hx + k % 3], wp[k], acc);
            }
            acc += wd[B2OFF + o];
            Hw[o][hy][hx] = acc >= 0.0 ? acc : wd[P2OFF + o] * acc;
        }
        __syncthreads();
        if (t < 32) {
            double acc = 0.0;
            for (int c = 0; c < 16; ++c) {
                const double* wp = wd + W3OFF + (t * 16 + c) * 9;
                #pragma unroll
                for (int k = 0; k < 9; ++k)
                    acc = fma(Hw[c][k / 3][k % 3], wp[k], acc);
            }
            acc += wd[B3OFF + t];
            vch[t] = acc >= 0.0 ? acc : wd[P3OFF + t] * acc;
        }
        __syncthreads();
        if (t == 0) {
            double c0 = wd[BAOFF + 0], c1 = wd[BAOFF + 1];
            for (int o = 0; o < 32; ++o) {
                c0 = fma(wd[WAOFF + o], vch[o], c0);
                c1 = fma(wd[WAOFF + 32 + o], vch[o], c1);
            }
            double mx = fmax(c0, c1);
            double e0 = exp(c0 - mx), e1 = exp(c1 - mx);
            double prob = e1 / (e0 + e1);
            if (prob >= 0.6) {
                double r0 = wd[BBOFF+0], r1 = wd[BBOFF+1], r2 = wd[BBOFF+2], r3 = wd[BBOFF+3];
                for (int o = 0; o < 32; ++o) {
                    double v = vch[o];
                    r0 = fma(wd[WBOFF + o], v, r0);
                    r1 = fma(wd[WBOFF + 32 + o], v, r1);
                    r2 = fma(wd[WBOFF + 64 + o], v, r2);
                    r3 = fma(wd[WBOFF + 96 + o], v, r3);
                }
                double fx = (double)x3, fy = (double)y3;
                double cx = (fx * 2.0 + 6.0) / 0.6;
                double cy = (fy * 2.0 + 6.0) / 0.6;
                double ww = 12.0 / 0.6, hw = ww / 2.0;
                double* bp = boxplane + (size_t)idx * 5;
                bp[0] = cx - hw + r0 * ww;
                bp[1] = cy - hw + r1 * ww;
                bp[2] = cx + hw + r2 * ww;
                bp[3] = cy + hw + r3 * ww;
                bp[4] = prob;
                u64 bits = (u64)__double_as_longlong(prob);
                u64 kh = (bits - 0x3FE0000000000000ull) >> 9;
                int slot = atomicAdd(&ctrl[1], 1);
                keys[slot] = (kh << 20) | ((u64)(~idx) & IDXMASK);
            }
        }
        __syncthreads();
    }
}

// ------- pass B: each block sorts 4 chunks of 512, keeps local top-512 (desc) -------
__global__ __launch_bounds__(512) void k_sortchunks(
    const u64* __restrict__ cand, const int* __restrict__ ctrl,
    u64* __restrict__ sorted)
{
    __shared__ u64 stop_[512];
    __shared__ u64 schunk[512];
    int tid = threadIdx.x;
    int n = ctrl[1]; if (n > NPIX) n = NPIX;
    long base0 = (long)blockIdx.x * 2048;
    stop_[tid] = 0ull;
    if (base0 < n) {
        for (int s = 0; s < 4; ++s) {
            long base = base0 + (long)s * 512;
            if (base >= n) break;
            schunk[tid] = (base + tid < n) ? cand[base + tid] : 0ull;
            for (int k = 2; k <= 512; k <<= 1)
                for (int j = k >> 1; j > 0; j >>= 1) {
                    __syncthreads();
                    int ixj = tid ^ j;
                    if (ixj > tid) {
                        u64 a = schunk[tid], b = schunk[ixj];
                        bool desc = ((tid & k) == 0);
                        if (desc ? (a < b) : (a > b)) { schunk[tid] = b; schunk[ixj] = a; }
                    }
                }
            __syncthreads();
            u64 m = stop_[tid], v = schunk[511 - tid];
            stop_[tid] = m > v ? m : v;
            for (int j = 256; j > 0; j >>= 1) {
                __syncthreads();
                int ixj = tid ^ j;
                if (ixj > tid) {
                    u64 a = stop_[tid], b = stop_[ixj];
                    if (a < b) { stop_[tid] = b; stop_[ixj] = a; }
                }
            }
            __syncthreads();
        }
    }
    sorted[(size_t)blockIdx.x * 512 + tid] = stop_[tid];
}

// ------- merge 8 consecutive sorted-512 lists -> one sorted-512 -------
__global__ __launch_bounds__(512) void k_merge8(
    const u64* __restrict__ in, u64* __restrict__ out, int nin)
{
    __shared__ u64 s[512];
    int tid = threadIdx.x;
    int base = blockIdx.x * 8;
    s[tid] = (base < nin) ? in[(size_t)base * 512 + tid] : 0ull;
    for (int c = 1; c < 8; ++c) {
        int li = base + c;
        u64 v = (li < nin) ? in[(size_t)li * 512 + (511 - tid)] : 0ull;
        __syncthreads();
        u64 m = s[tid];
        s[tid] = m > v ? m : v;
        for (int j = 256; j > 0; j >>= 1) {
            __syncthreads();
            int ixj = tid ^ j;
            if (ixj > tid) {
                u64 a = s[tid], b = s[ixj];
                if (a < b) { s[tid] = b; s[ixj] = a; }
            }
        }
        __syncthreads();
    }
    out[(size_t)blockIdx.x * 512 + tid] = s[tid];
}

// ------- boxmat: parallel build of both suppression bit-matrices + box SoA -------
__global__ __launch_bounds__(512) void k_boxmat(
    const u64* __restrict__ lists, const double* __restrict__ boxplane,
    u64* __restrict__ mats, double* __restrict__ bxs, u64* __restrict__ validw)
{
    __shared__ double sx1[512], sy1[512], sx2[512], sy2[512], sar[512];
    int tid = threadIdx.x;
    u64 key = lists[tid];
    bool valid = key != 0ull;
    double x1 = 0.0, y1 = 0.0, x2 = 0.0, y2 = 0.0, score = 0.0;
    if (valid) {
        u32 idx = (u32)(IDXMASK - (key & IDXMASK));
        const double* bp = boxplane + (size_t)idx * 5;
        x1 = bp[0]; y1 = bp[1]; x2 = bp[2]; y2 = bp[3]; score = bp[4];
    }
    double area = (x2 - x1) * (y2 - y1);
    sx1[tid] = x1; sy1[tid] = y1; sx2[tid] = x2; sy2[tid] = y2; sar[tid] = area;
    if (blockIdx.x == 0 && blockIdx.y == 0) {
        bxs[tid] = x1; bxs[512 + tid] = y1; bxs[1024 + tid] = x2;
        bxs[1536 + tid] = y2; bxs[2048 + tid] = score;
        u64 bal = __ballot(valid);
        if ((tid & 63) == 0) validw[tid >> 6] = bal;
    }
    __syncthreads();
    double thr = (blockIdx.y == 0) ? 0.5 : 0.7;
    int wv = tid >> 6;
    int rowbase = blockIdx.x * 64;
    for (int r = 0; r < 64; ++r) {
        int i = rowbase + r;
        double ix1 = fmax(sx1[i], x1);
        double iy1 = fmax(sy1[i], y1);
        double ix2 = fmin(sx2[i], x2);
        double iy2 = fmin(sy2[i], y2);
        double inter = fmax(ix2 - ix1, 0.0) * fmax(iy2 - iy1, 0.0);
        double uni = sar[i] + area - inter + 1e-9;
        bool sup = (uni > 0.0) && (inter > thr * uni) && (tid > i);
        u64 w = __ballot(sup);
        if ((tid & 63) == 0)
            mats[((size_t)blockIdx.y * 512 + i) * 8 + wv] = w;
    }
}

// ------- nmsfin: two serial greedy scans over precomputed matrices; output -------
__global__ __launch_bounds__(512) void k_nmsfin(
    const u64* __restrict__ mats, const double* __restrict__ bxs,
    const u64* __restrict__ validw, float* __restrict__ out)
{
    __shared__ u64 keepw[8];
    int tid = threadIdx.x;
    if (tid < 8) keepw[tid] = validw[tid];
    __syncthreads();
    for (int pass = 0; pass < 2; ++pass) {
        if (tid < 64) {
            const u64* mat = mats + (size_t)pass * 512 * 8;
            u64 kw = (tid < 8) ? keepw[tid] : 0ull;
            for (int i = 0; i < 512; ++i) {
                u64 row = mat[i * 8 + (tid & 7)];
                u64 cur = __shfl(kw, i >> 6);
                if ((cur >> (i & 63)) & 1) kw &= ~row;
            }
            if (tid < 8) keepw[tid] = kw;
        }
        __syncthreads();
    }
    double kf = ((keepw[tid >> 6] >> (tid & 63)) & 1) ? 1.0 : 0.0;
    out[tid * 5 + 0] = (float)(bxs[tid] * kf);
    out[tid * 5 + 1] = (float)(bxs[512 + tid] * kf);
    out[tid * 5 + 2] = (float)(bxs[1024 + tid] * kf);
    out[tid * 5 + 3] = (float)(bxs[1536 + tid] * kf);
    out[tid * 5 + 4] = (float)(bxs[2048 + tid] * kf);
}

extern "C" void kernel_launch(void* const* d_in, const int* in_sizes, int n_in,
                              void* d_out, int out_size, void* d_ws, size_t ws_size,
                              hipStream_t stream)
{
    const float* x  = (const float*)d_in[0];
    const float* w1 = (const float*)d_in[1];
    const float* b1 = (const float*)d_in[2];
    const float* p1 = (const float*)d_in[3];
    const float* w2 = (const float*)d_in[4];
    const float* b2 = (const float*)d_in[5];
    const float* p2 = (const float*)d_in[6];
    const float* w3 = (const float*)d_in[7];
    const float* b3 = (const float*)d_in[8];
    const float* p3 = (const float*)d_in[9];
    const float* wa = (const float*)d_in[10];
    const float* ba = (const float*)d_in[11];
    const float* wb = (const float*)d_in[12];
    const float* bb = (const float*)d_in[13];
    float* out = (float*)d_out;

    char* ws = (char*)d_ws;
    float*  Pf    = (float*) (ws);                       // 10*1023*1024*4 = 41,902,080
    float*  H2f   = (float*) (ws + 41902080);            // 16*1021*1024*4 = 66,912,256
    float*  Lg    = (float*) (ws + 108814336);           // NPIX*4 -> 4,153,600
    u32*    ghist = (u32*)   (ws + 112967936);           // 8192
    int*    ctrl  = (int*)   (ws + 112976128);           // 256: [0]=selcnt [1]=emit
    u32*    selidx= (u32*)   (ws + 112976384);           // NPIX*4 -> 4,153,600
    u64*    keys  = (u64*)   (ws + 117129984);           // NPIX*8 -> 8,307,200
    u64*    sorted= (u64*)   (ws + 125437184);           // 508*512*8 = 2,080,768
    u64*    l1out = (u64*)   (ws + 127517952);           // 64*512*8 = 262,144
    u64*    l2out = (u64*)   (ws + 127780096);           // 8*512*8 = 32,768
    double* boxpl = (double*)(ws + 127812864);           // NPIX*5*8 -> 41,534,720
    double* wd    = (double*)(ws + 169347584);           // WDTOT*8 = 53,056
    u64*    l3out = (u64*)   (ws + 125437184);           // aliases sorted (free by then)
    u64*    mats  = (u64*)   (ws + 125441280);           // 2*512*8*8 = 65,536
    double* bxs   = (double*)(ws + 125506816);           // 5*512*8 = 20,480
    u64*    vwords= (u64*)   (ws + 125527296);           // 64

    k_prep<<<1, 256, 0, stream>>>(w1, b1, p1, w2, b2, p2, w3, b3, p3, wa, ba, wb, bb, wd, ctrl, ghist);
    k_conv1f<<<dim3(16, 256), dim3(64, 4), 0, stream>>>(x, w1, b1, p1, Pf);
    k_conv2f<<<dim3(1, W2H), dim3(64, 4), 0, stream>>>(Pf, w2, b2, p2, H2f);
    k_conv3f<<<dim3(1, W3H), dim3(64, 8), 0, stream>>>(H2f, w3, b3, p3, wa, ba, Lg, ghist);
    k_select<<<1024, 256, 0, stream>>>(Lg, ghist, ctrl, selidx);
    k_recomp<<<2048, 64, 0, stream>>>(x, wd, selidx, ctrl, keys, boxpl);
    k_sortchunks<<<508, 512, 0, stream>>>(keys, ctrl, sorted);
    k_merge8<<<64, 512, 0, stream>>>(sorted, l1out, 508);
    k_merge8<<<8, 512, 0, stream>>>(l1out, l2out, 64);
    k_merge8<<<1, 512, 0, stream>>>(l2out, l3out, 8);
    k_boxmat<<<dim3(8, 2), 512, 0, stream>>>(l3out, boxpl, mats, bxs, vwords);
    k_nmsfin<<<1, 512, 0, stream>>>(mats, bxs, vwords, out);
}

// Round 12
// 566.382 us; speedup vs baseline: 4.9671x; 1.0312x over previous
//
#include <hip/hip_runtime.h>

typedef unsigned long long u64;
typedef unsigned int u32;

#define W1H 1023   // after conv1+pool
#define W2H 1021   // after conv2
#define W3H 1019   // after conv3
#define NPIX (W3H * W3H)          // 1,038,361 < 2^20
#define IDXMASK 0xFFFFFull
#define PSTR 1024                 // padded row stride for P / H2 planes

#define NBINS 2048
#define HLO 0.3055f      // ln(1.5) - 0.10
#define HW_ 0.025f       // bin width
#define HINV 40.0f       // 1/HW_
#define HDELTA 0.10f     // selection margin (>= 2*|f32-f64| logit error)

// f64 weight arena offsets (in doubles)
#define W1OFF 0
#define B1OFF 270
#define P1OFF 280
#define W2OFF 290
#define B2OFF 1730
#define P2OFF 1746
#define W3OFF 1762
#define B3OFF 6370
#define P3OFF 6402
#define WAOFF 6434
#define BAOFF 6498
#define WBOFF 6500
#define BBOFF 6628
#define WDTOT 6632

// bijective XCD-aware row swizzle (m204): contiguous row band per XCD
__device__ __forceinline__ int xcd_swizzle(int bid, int nwg) {
    int q = nwg >> 3, r = nwg & 7;
    int x = bid & 7, i = bid >> 3;
    return (x < r ? x * (q + 1) : r * (q + 1) + (x - r) * q) + i;
}

// ---- prep: convert weights to f64; zero ctrl + hist ----
__global__ __launch_bounds__(256) void k_prep(
    const float* __restrict__ w1, const float* __restrict__ b1, const float* __restrict__ p1,
    const float* __restrict__ w2, const float* __restrict__ b2, const float* __restrict__ p2,
    const float* __restrict__ w3, const float* __restrict__ b3, const float* __restrict__ p3,
    const float* __restrict__ wa, const float* __restrict__ ba,
    const float* __restrict__ wb, const float* __restrict__ bb,
    double* __restrict__ wd, int* __restrict__ ctrl, u32* __restrict__ ghist)
{
    int t = threadIdx.x;
    if (t < 2) ctrl[t] = 0;
    for (int i = t; i < NBINS; i += 256) ghist[i] = 0u;
    for (int i = t; i < 270; i += 256)  wd[W1OFF + i] = (double)w1[i];
    if (t < 10) { wd[B1OFF + t] = (double)b1[t]; wd[P1OFF + t] = (double)p1[t]; }
    for (int i = t; i < 1440; i += 256) wd[W2OFF + i] = (double)w2[i];
    if (t < 16) { wd[B2OFF + t] = (double)b2[t]; wd[P2OFF + t] = (double)p2[t]; }
    for (int i = t; i < 4608; i += 256) wd[W3OFF + i] = (double)w3[i];
    if (t < 32) { wd[B3OFF + t] = (double)b3[t]; wd[P3OFF + t] = (double)p3[t]; }
    if (t < 64)  wd[WAOFF + t] = (double)wa[t];
    if (t < 2)   wd[BAOFF + t] = (double)ba[t];
    if (t < 128) wd[WBOFF + t] = (double)wb[t];
    if (t < 4)   wd[BBOFF + t] = (double)bb[t];
}

// ---------------- conv1 f32 (3->10) + bias + prelu + maxpool2, LDS-staged x ----------------
__global__ __launch_bounds__(256) void k_conv1f(
    const float* __restrict__ x, const float* __restrict__ w1,
    const float* __restrict__ b1, const float* __restrict__ p1,
    float* __restrict__ P)
{
    __shared__ float sw[270];
    __shared__ float sb[10], sp[10];
    __shared__ float xs[3][10][132];
    int tx = threadIdx.x, ty = threadIdx.y;
    int t = ty * 64 + tx;
    for (int i = t; i < 270; i += 256) sw[i] = w1[i];
    if (t < 10) { sb[t] = b1[t]; sp[t] = p1[t]; }
    int bx = blockIdx.x, by = blockIdx.y;
    const float4* x4 = (const float4*)x;
    for (int i = t; i < 990; i += 256) {
        int c = i / 330, rem = i % 330, r = rem / 33, k = rem % 33;
        int row = 8 * by + r; if (row > 2047) row = 2047;
        int col4 = bx * 32 + k; if (col4 > 511) col4 = 511;
        float4 v = x4[((size_t)c * 2048 + row) * 512 + col4];
        xs[c][r][k * 4 + 0] = v.x; xs[c][r][k * 4 + 1] = v.y;
        xs[c][r][k * 4 + 2] = v.z; xs[c][r][k * 4 + 3] = v.w;
    }
    __syncthreads();
    int px = bx * 64 + tx;
    int py = by * 4 + ty;
    if (px >= W1H || py >= W1H) return;
    float acc[10][4];
    #pragma unroll
    for (int ch = 0; ch < 10; ++ch) { acc[ch][0]=0.f; acc[ch][1]=0.f; acc[ch][2]=0.f; acc[ch][3]=0.f; }
    for (int c = 0; c < 3; ++c) {
        float in[4][4];
        #pragma unroll
        for (int u = 0; u < 4; ++u) {
            in[u][0] = xs[c][2*ty+u][2*tx+0];
            in[u][1] = xs[c][2*ty+u][2*tx+1];
            in[u][2] = xs[c][2*ty+u][2*tx+2];
            in[u][3] = xs[c][2*ty+u][2*tx+3];
        }
        #pragma unroll
        for (int ch = 0; ch < 10; ++ch) {
            const float* wp = sw + (ch * 3 + c) * 9;
            #pragma unroll
            for (int u = 0; u < 3; ++u)
                #pragma unroll
                for (int v = 0; v < 3; ++v) {
                    float w = wp[u * 3 + v];
                    acc[ch][0] = fmaf(in[u][v],         w, acc[ch][0]);
                    acc[ch][1] = fmaf(in[u][v + 1],     w, acc[ch][1]);
                    acc[ch][2] = fmaf(in[u + 1][v],     w, acc[ch][2]);
                    acc[ch][3] = fmaf(in[u + 1][v + 1], w, acc[ch][3]);
                }
        }
    }
    #pragma unroll
    for (int ch = 0; ch < 10; ++ch) {
        float m = fmaxf(fmaxf(acc[ch][0], acc[ch][1]), fmaxf(acc[ch][2], acc[ch][3])) + sb[ch];
        float r = m >= 0.f ? m : sp[ch] * m;
        P[((size_t)ch * W1H + py) * PSTR + px] = r;
    }
}

// ------- conv2 f32 (10->16) + bias + prelu: 8px x 8och per thread -------
__global__ __launch_bounds__(256) void k_conv2f(
    const float* __restrict__ P, const float* __restrict__ w2,
    const float* __restrict__ b2, const float* __restrict__ p2,
    float* __restrict__ H2)
{
    __shared__ __align__(16) float sw[10 * 16 * 12]; // [c][o][12] f4-padded
    __shared__ float sb[16], sp[16];
    int tx = threadIdx.x, ty = threadIdx.y;
    int t = ty * 64 + tx;
    for (int i = t; i < 1440; i += 256) {
        int o = i / 90, r = i % 90, c = r / 9, k = r % 9;
        sw[(c * 16 + o) * 12 + k] = w2[i];
    }
    if (t < 16) { sb[t] = b2[t]; sp[t] = p2[t]; }
    __syncthreads();
    int py = xcd_swizzle(blockIdx.y, W2H);
    int och0 = (ty & 1) * 8;
    int px_base = (ty >> 1) * 512 + tx * 8;
    float acc[8][8];
    #pragma unroll
    for (int j = 0; j < 8; ++j)
        #pragma unroll
        for (int p = 0; p < 8; ++p) acc[j][p] = 0.f;

    #pragma unroll 2
    for (int c = 0; c < 10; ++c) {
        float f[3][12];
        #pragma unroll
        for (int u = 0; u < 3; ++u) {
            const float* row = P + ((size_t)c * W1H + (py + u)) * PSTR + px_base;
            float4 a = *(const float4*)(row);
            float4 b = *(const float4*)(row + 4);
            float4 d = *(const float4*)(row + 8);
            f[u][0]=a.x; f[u][1]=a.y; f[u][2]=a.z;  f[u][3]=a.w;
            f[u][4]=b.x; f[u][5]=b.y; f[u][6]=b.z;  f[u][7]=b.w;
            f[u][8]=d.x; f[u][9]=d.y; f[u][10]=d.z; f[u][11]=d.w;
        }
        #pragma unroll
        for (int j = 0; j < 8; ++j) {
            int o = och0 + j;
            const float4* wv = (const float4*)(sw + (c * 16 + o) * 12);
            float4 wA = wv[0], wB = wv[1], wC = wv[2];
            float w[9] = {wA.x,wA.y,wA.z,wA.w,wB.x,wB.y,wB.z,wB.w,wC.x};
            #pragma unroll
            for (int u = 0; u < 3; ++u)
                #pragma unroll
                for (int v = 0; v < 3; ++v) {
                    float wt = w[u*3+v];
                    #pragma unroll
                    for (int p = 0; p < 8; ++p)
                        acc[j][p] = fmaf(f[u][p+v], wt, acc[j][p]);
                }
        }
    }
    #pragma unroll
    for (int j = 0; j < 8; ++j) {
        int o = och0 + j;
        float bb_ = sb[o], pp_ = sp[o];
        #pragma unroll
        for (int p = 0; p < 8; ++p) {
            int px = px_base + p;
            if (px < W2H) {
                float v = acc[j][p] + bb_;
                v = v >= 0.f ? v : pp_ * v;
                H2[((size_t)o * W2H + py) * PSTR + px] = v;
            }
        }
    }
}

// ------- conv3 f32 (16->32) + prelu + cls head: 8px x 8och per thread -------
__global__ __launch_bounds__(512, 2) void k_conv3f(
    const float* __restrict__ H2, const float* __restrict__ w3,
    const float* __restrict__ b3, const float* __restrict__ p3,
    const float* __restrict__ wa, const float* __restrict__ ba,
    float* __restrict__ Lg, u32* __restrict__ ghist)
{
    __shared__ __align__(16) float sw[16 * 32 * 12];   // 24576 B
    __shared__ float spart[4][1024];                   // 16384 B
    __shared__ u32 hist[NBINS];                        // 8192 B
    __shared__ float sb[32], sp[32], swd[32];
    __shared__ float slgb;
    int tx = threadIdx.x, ty = threadIdx.y;
    int t = ty * 64 + tx;
    for (int i = t; i < 4608; i += 512) {
        int o = i / 144, rem = i % 144, c = rem / 9, k = rem % 9;
        sw[(c * 32 + o) * 12 + k] = w3[i];
    }
    if (t < 32) { sb[t] = b3[t]; sp[t] = p3[t]; swd[t] = wa[32 + t] - wa[t]; }
    if (t == 0) slgb = ba[1] - ba[0];
    for (int i = t; i < NBINS; i += 512) hist[i] = 0u;
    __syncthreads();

    int py = xcd_swizzle(blockIdx.y, W3H);
    int och0 = (ty & 3) * 8;
    int px_base = (ty >> 2) * 512 + tx * 8;
    float acc[8][8];
    #pragma unroll
    for (int j = 0; j < 8; ++j)
        #pragma unroll
        for (int p = 0; p < 8; ++p) acc[j][p] = 0.f;

    #pragma unroll 2
    for (int c = 0; c < 16; ++c) {
        float f[3][12];
        #pragma unroll
        for (int u = 0; u < 3; ++u) {
            const float* row = H2 + ((size_t)c * W2H + (py + u)) * PSTR + px_base;
            float4 a = *(const float4*)(row);
            float4 b = *(const float4*)(row + 4);
            float4 d = *(const float4*)(row + 8);
            f[u][0]=a.x; f[u][1]=a.y; f[u][2]=a.z;  f[u][3]=a.w;
            f[u][4]=b.x; f[u][5]=b.y; f[u][6]=b.z;  f[u][7]=b.w;
            f[u][8]=d.x; f[u][9]=d.y; f[u][10]=d.z; f[u][11]=d.w;
        }
        #pragma unroll
        for (int j = 0; j < 8; ++j) {
            int o = och0 + j;
            const float4* wv = (const float4*)(sw + (c * 32 + o) * 12);
            float4 wA = wv[0], wB = wv[1], wC = wv[2];
            float w[9] = {wA.x,wA.y,wA.z,wA.w,wB.x,wB.y,wB.z,wB.w,wC.x};
            #pragma unroll
            for (int u = 0; u < 3; ++u)
                #pragma unroll
                for (int v = 0; v < 3; ++v) {
                    float wt = w[u*3+v];
                    #pragma unroll
                    for (int p = 0; p < 8; ++p)
                        acc[j][p] = fmaf(f[u][p+v], wt, acc[j][p]);
                }
        }
    }

    // per-thread partial logit over its 8 channels
    float partv[8];
    #pragma unroll
    for (int p = 0; p < 8; ++p) partv[p] = 0.f;
    #pragma unroll
    for (int j = 0; j < 8; ++j) {
        int o = och0 + j;
        float bb_ = sb[o], pp_ = sp[o], wdd = swd[o];
        #pragma unroll
        for (int p = 0; p < 8; ++p) {
            float v = acc[j][p] + bb_;
            v = v >= 0.f ? v : pp_ * v;
            partv[p] = fmaf(wdd, v, partv[p]);
        }
    }
    #pragma unroll
    for (int p = 0; p < 8; ++p) spart[ty & 3][px_base + p] = partv[p];
    __syncthreads();

    // reduce 4 partials per pixel; thread t owns px t and t+512
    #pragma unroll
    for (int rep = 0; rep < 2; ++rep) {
        int pl = t + rep * 512;
        float lg = slgb;
        #pragma unroll
        for (int g = 0; g < 4; ++g) lg += spart[g][pl];
        if (pl < W3H) {
            Lg[(size_t)py * W3H + pl] = lg;
            if (lg >= HLO) {
                int bin = (int)((lg - HLO) * HINV);
                if (bin > NBINS - 1) bin = NBINS - 1;
                atomicAdd(&hist[bin], 1u);
            }
        }
    }
    __syncthreads();
    for (int i = t; i < NBINS; i += 512) {
        u32 v = hist[i];
        if (v) atomicAdd(&ghist[i], v);
    }
}

// ---- select (with fused threshold scan): pixels with f32 logit >= Tsel ----
__global__ __launch_bounds__(256) void k_select(
    const float* __restrict__ Lg, const u32* __restrict__ ghist,
    int* __restrict__ ctrl, u32* __restrict__ selidx)
{
    __shared__ u32 h[NBINS];
    __shared__ u32 tsum[256];
    __shared__ int best;
    __shared__ float sT;
    int t = threadIdx.x;
    for (int i = t; i < NBINS; i += 256) h[i] = ghist[i];
    if (t == 0) best = -1;
    __syncthreads();
    u32 s = 0;
    #pragma unroll
    for (int k = 0; k < 8; ++k) s += h[t * 8 + k];
    tsum[t] = s;
    __syncthreads();
    for (int off = 1; off < 256; off <<= 1) {
        u32 add = (t + off < 256) ? tsum[t + off] : 0u;
        __syncthreads();
        tsum[t] += add;
        __syncthreads();
    }
    u32 cum = (t < 255) ? tsum[t + 1] : 0u;
    int cand = -1;
    for (int k = 7; k >= 0; --k) {
        cum += h[t * 8 + k];
        if (cand < 0 && cum >= 512) cand = t * 8 + k;
    }
    if (cand >= 0) atomicMax(&best, cand);
    __syncthreads();
    if (t == 0) sT = (best < 0) ? HLO : (HLO + (float)best * HW_ - HDELTA);
    __syncthreads();
    float T = sT;
    int stride = gridDim.x * 256;
    const float4* Lg4 = (const float4*)Lg;
    int n4 = NPIX >> 2;                       // 259590; tail = 1 elem
    for (int i = blockIdx.x * 256 + t; i < n4; i += stride) {
        float4 v = Lg4[i];
        if (v.x >= T) { int s_ = atomicAdd(&ctrl[0], 1); selidx[s_] = (u32)(i * 4 + 0); }
        if (v.y >= T) { int s_ = atomicAdd(&ctrl[0], 1); selidx[s_] = (u32)(i * 4 + 1); }
        if (v.z >= T) { int s_ = atomicAdd(&ctrl[0], 1); selidx[s_] = (u32)(i * 4 + 2); }
        if (v.w >= T) { int s_ = atomicAdd(&ctrl[0], 1); selidx[s_] = (u32)(i * 4 + 3); }
    }
    if (blockIdx.x == 0 && t == 0) {
        if (Lg[NPIX - 1] >= T) { int s_ = atomicAdd(&ctrl[0], 1); selidx[s_] = (u32)(NPIX - 1); }
    }
}

// ---- recompute: exact f64 pyramid per selected pixel; emit key + boxes ----
__global__ __launch_bounds__(64) void k_recomp(
    const float* __restrict__ x, const double* __restrict__ wd,
    const u32* __restrict__ selidx, int* __restrict__ ctrl,
    u64* __restrict__ keys, double* __restrict__ boxplane)
{
    __shared__ double xw[3][12][12];
    __shared__ double Pw[10][5][5];
    __shared__ double Hw[16][3][3];
    __shared__ double vch[32];
    int nsel = ctrl[0]; if (nsel > NPIX) nsel = NPIX;
    int t = threadIdx.x;
    for (int s = blockIdx.x; s < nsel; s += gridDim.x) {
        u32 idx = selidx[s];
        int y3 = (int)(idx / W3H), x3 = (int)(idx % W3H);
        int xr = 2 * y3, xc = 2 * x3;
        for (int i = t; i < 432; i += 64) {
            int c = i / 144, r = (i % 144) / 12, cc = i % 12;
            xw[c][r][cc] = (double)x[((size_t)c * 2048 + (xr + r)) * 2048 + (xc + cc)];
        }
        __syncthreads();
        for (int i = t; i < 250; i += 64) {
            int ch = i / 25, py = (i % 25) / 5, px = i % 5;
            int r0 = py * 2, c0 = px * 2;
            double a00=0.0, a01=0.0, a10=0.0, a11=0.0;
            for (int c = 0; c < 3; ++c) {
                const double* wp = wd + W1OFF + (ch * 3 + c) * 9;
                #pragma unroll
                for (int u = 0; u < 3; ++u)
                    #pragma unroll
                    for (int v = 0; v < 3; ++v) {
                        double w = wp[u * 3 + v];
                        a00 = fma(xw[c][r0+u][c0+v],     w, a00);
                        a01 = fma(xw[c][r0+u][c0+v+1],   w, a01);
                        a10 = fma(xw[c][r0+u+1][c0+v],   w, a10);
                        a11 = fma(xw[c][r0+u+1][c0+v+1], w, a11);
                    }
            }
            double m = fmax(fmax(a00, a01), fmax(a10, a11)) + wd[B1OFF + ch];
            Pw[ch][py][px] = m >= 0.0 ? m : wd[P1OFF + ch] * m;
        }
        __syncthreads();
        for (int i = t; i < 144; i += 64) {
            int o = i / 9, hy = (i % 9) / 3, hx = i % 3;
            double acc = 0.0;
            for (int c = 0; c < 10; ++c) {
                const double* wp = wd + W2OFF + (o * 10 + c) * 9;
                #pragma unroll
                for (int k = 0; k < 9; ++k)
                    acc = fma(Pw[c][hy + k / 3][hx + k % 3], wp[k], acc);
            }
            acc += wd[B2OFF + o];
            Hw[o][hy][hx] = acc >= 0.0 ? acc : wd[P2OFF + o] * acc;
        }
        __syncthreads();
        if (t < 32) {
            double acc = 0.0;
            for (int c = 0; c < 16; ++c) {
                const double* wp = wd + W3OFF + (t * 16 + c) * 9;
                #pragma unroll
                for (int k = 0; k < 9; ++k)
                    acc = fma(Hw[c][k / 3][k % 3], wp[k], acc);
            }
            acc += wd[B3OFF + t];
            vch[t] = acc >= 0.0 ? acc : wd[P3OFF + t] * acc;
        }
        __syncthreads();
        if (t == 0) {
            double c0 = wd[BAOFF + 0], c1 = wd[BAOFF + 1];
            for (int o = 0; o < 32; ++o) {
                c0 = fma(wd[WAOFF + o], vch[o], c0);
                c1 = fma(wd[WAOFF + 32 + o], vch[o], c1);
            }
            double mx = fmax(c0, c1);
            double e0 = exp(c0 - mx), e1 = exp(c1 - mx);
            double prob = e1 / (e0 + e1);
            if (prob >= 0.6) {
                double r0 = wd[BBOFF+0], r1 = wd[BBOFF+1], r2 = wd[BBOFF+2], r3 = wd[BBOFF+3];
                for (int o = 0; o < 32; ++o) {
                    double v = vch[o];
                    r0 = fma(wd[WBOFF + o], v, r0);
                    r1 = fma(wd[WBOFF + 32 + o], v, r1);
                    r2 = fma(wd[WBOFF + 64 + o], v, r2);
                    r3 = fma(wd[WBOFF + 96 + o], v, r3);
                }
                double fx = (double)x3, fy = (double)y3;
                double cx = (fx * 2.0 + 6.0) / 0.6;
                double cy = (fy * 2.0 + 6.0) / 0.6;
                double ww = 12.0 / 0.6, hw = ww / 2.0;
                double* bp = boxplane + (size_t)idx * 5;
                bp[0] = cx - hw + r0 * ww;
                bp[1] = cy - hw + r1 * ww;
                bp[2] = cx + hw + r2 * ww;
                bp[3] = cy + hw + r3 * ww;
                bp[4] = prob;
                u64 bits = (u64)__double_as_longlong(prob);
                u64 kh = (bits - 0x3FE0000000000000ull) >> 9;
                int slot = atomicAdd(&ctrl[1], 1);
                keys[slot] = (kh << 20) | ((u64)(~idx) & IDXMASK);
            }
        }
        __syncthreads();
    }
}

// ------- top8: 8 blocks grid-stride over 512-chunks, each keeps running top-512 -------
__global__ __launch_bounds__(512) void k_top8(
    const u64* __restrict__ keys, const int* __restrict__ ctrl,
    u64* __restrict__ lists8)
{
    __shared__ u64 stop_[512];
    __shared__ u64 schunk[512];
    int tid = threadIdx.x;
    int n = ctrl[1]; if (n > NPIX) n = NPIX;
    int nchunks = (n + 511) / 512;
    stop_[tid] = 0ull;
    for (int c = blockIdx.x; c < nchunks; c += 8) {
        long base = (long)c * 512;
        schunk[tid] = (base + tid < n) ? keys[base + tid] : 0ull;
        for (int k = 2; k <= 512; k <<= 1)
            for (int j = k >> 1; j > 0; j >>= 1) {
                __syncthreads();
                int ixj = tid ^ j;
                if (ixj > tid) {
                    u64 a = schunk[tid], b = schunk[ixj];
                    bool desc = ((tid & k) == 0);
                    if (desc ? (a < b) : (a > b)) { schunk[tid] = b; schunk[ixj] = a; }
                }
            }
        __syncthreads();
        u64 m = stop_[tid], v = schunk[511 - tid];
        stop_[tid] = m > v ? m : v;
        for (int j = 256; j > 0; j >>= 1) {
            __syncthreads();
            int ixj = tid ^ j;
            if (ixj > tid) {
                u64 a = stop_[tid], b = stop_[ixj];
                if (a < b) { stop_[tid] = b; stop_[ixj] = a; }
            }
        }
        __syncthreads();
    }
    lists8[(size_t)blockIdx.x * 512 + tid] = stop_[tid];
}

// ------- mergefin: merge 8 sorted lists -> final top-512; fill box SoA + valid words -------
__global__ __launch_bounds__(512) void k_mergefin(
    const u64* __restrict__ lists8, const double* __restrict__ boxplane,
    u64* __restrict__ l3out, double* __restrict__ bxs, u64* __restrict__ validw)
{
    __shared__ u64 s[512];
    int tid = threadIdx.x;
    s[tid] = lists8[tid];
    for (int c = 1; c < 8; ++c) {
        u64 v = lists8[(size_t)c * 512 + (511 - tid)];
        __syncthreads();
        u64 m = s[tid];
        s[tid] = m > v ? m : v;
        for (int j = 256; j > 0; j >>= 1) {
            __syncthreads();
            int ixj = tid ^ j;
            if (ixj > tid) {
                u64 a = s[tid], b = s[ixj];
                if (a < b) { s[tid] = b; s[ixj] = a; }
            }
        }
        __syncthreads();
    }
    u64 key = s[tid];
    l3out[tid] = key;
    bool valid = key != 0ull;
    double x1 = 0.0, y1 = 0.0, x2 = 0.0, y2 = 0.0, score = 0.0;
    if (valid) {
        u32 idx = (u32)(IDXMASK - (key & IDXMASK));
        const double* bp = boxplane + (size_t)idx * 5;
        x1 = bp[0]; y1 = bp[1]; x2 = bp[2]; y2 = bp[3]; score = bp[4];
    }
    bxs[tid] = x1; bxs[512 + tid] = y1; bxs[1024 + tid] = x2;
    bxs[1536 + tid] = y2; bxs[2048 + tid] = score;
    u64 bal = __ballot(valid);
    if ((tid & 63) == 0) validw[tid >> 6] = bal;
}

// ------- boxmat: parallel build of both suppression bit-matrices -------
// grid (8, 2): blockIdx.x = 64-row group, blockIdx.y = pass (thr .5 / .7)
__global__ __launch_bounds__(512) void k_boxmat(
    const u64* __restrict__ l3out, const double* __restrict__ boxplane,
    u64* __restrict__ mats)
{
    __shared__ double sx1[512], sy1[512], sx2[512], sy2[512], sar[512];
    int tid = threadIdx.x;
    u64 key = l3out[tid];
    bool valid = key != 0ull;
    double x1 = 0.0, y1 = 0.0, x2 = 0.0, y2 = 0.0;
    if (valid) {
        u32 idx = (u32)(IDXMASK - (key & IDXMASK));
        const double* bp = boxplane + (size_t)idx * 5;
        x1 = bp[0]; y1 = bp[1]; x2 = bp[2]; y2 = bp[3];
    }
    double area = (x2 - x1) * (y2 - y1);
    sx1[tid] = x1; sy1[tid] = y1; sx2[tid] = x2; sy2[tid] = y2; sar[tid] = area;
    __syncthreads();
    double thr = (blockIdx.y == 0) ? 0.5 : 0.7;
    int wv = tid >> 6;
    int rowbase = blockIdx.x * 64;
    for (int r = 0; r < 64; ++r) {
        int i = rowbase + r;
        double ix1 = fmax(sx1[i], x1);
        double iy1 = fmax(sy1[i], y1);
        double ix2 = fmin(sx2[i], x2);
        double iy2 = fmin(sy2[i], y2);
        double inter = fmax(ix2 - ix1, 0.0) * fmax(iy2 - iy1, 0.0);
        double uni = sar[i] + area - inter + 1e-9;
        bool sup = (uni > 0.0) && (inter > thr * uni) && (tid > i);
        u64 w = __ballot(sup);
        if ((tid & 63) == 0)
            mats[((size_t)blockIdx.y * 512 + i) * 8 + wv] = w;
    }
}

// ------- nmsfin: two serial greedy scans over precomputed matrices; output -------
__global__ __launch_bounds__(512) void k_nmsfin(
    const u64* __restrict__ mats, const double* __restrict__ bxs,
    const u64* __restrict__ validw, float* __restrict__ out)
{
    __shared__ u64 keepw[8];
    int tid = threadIdx.x;
    if (tid < 8) keepw[tid] = validw[tid];
    __syncthreads();
    for (int pass = 0; pass < 2; ++pass) {
        if (tid < 64) {
            const u64* mat = mats + (size_t)pass * 512 * 8;
            u64 kw = (tid < 8) ? keepw[tid] : 0ull;
            for (int i = 0; i < 512; ++i) {
                u64 row = mat[i * 8 + (tid & 7)];
                u64 cur = __shfl(kw, i >> 6);
                if ((cur >> (i & 63)) & 1) kw &= ~row;
            }
            if (tid < 8) keepw[tid] = kw;
        }
        __syncthreads();
    }
    double kf = ((keepw[tid >> 6] >> (tid & 63)) & 1) ? 1.0 : 0.0;
    out[tid * 5 + 0] = (float)(bxs[tid] * kf);
    out[tid * 5 + 1] = (float)(bxs[512 + tid] * kf);
    out[tid * 5 + 2] = (float)(bxs[1024 + tid] * kf);
    out[tid * 5 + 3] = (float)(bxs[1536 + tid] * kf);
    out[tid * 5 + 4] = (float)(bxs[2048 + tid] * kf);
}

extern "C" void kernel_launch(void* const* d_in, const int* in_sizes, int n_in,
                              void* d_out, int out_size, void* d_ws, size_t ws_size,
                              hipStream_t stream)
{
    const float* x  = (const float*)d_in[0];
    const float* w1 = (const float*)d_in[1];
    const float* b1 = (const float*)d_in[2];
    const float* p1 = (const float*)d_in[3];
    const float* w2 = (const float*)d_in[4];
    const float* b2 = (const float*)d_in[5];
    const float* p2 = (const float*)d_in[6];
    const float* w3 = (const float*)d_in[7];
    const float* b3 = (const float*)d_in[8];
    const float* p3 = (const float*)d_in[9];
    const float* wa = (const float*)d_in[10];
    const float* ba = (const float*)d_in[11];
    const float* wb = (const float*)d_in[12];
    const float* bb = (const float*)d_in[13];
    float* out = (float*)d_out;

    char* ws = (char*)d_ws;
    float*  Pf    = (float*) (ws);                       // 10*1023*1024*4 = 41,902,080
    float*  H2f   = (float*) (ws + 41902080);            // 16*1021*1024*4 = 66,912,256
    float*  Lg    = (float*) (ws + 108814336);           // NPIX*4 -> 4,153,600
    u32*    ghist = (u32*)   (ws + 112967936);           // 8192
    int*    ctrl  = (int*)   (ws + 112976128);           // 256: [0]=selcnt [1]=emit
    u32*    selidx= (u32*)   (ws + 112976384);           // NPIX*4 -> 4,153,600
    u64*    keys  = (u64*)   (ws + 117129984);           // NPIX*8 -> 8,307,200
    u64*    lists8= (u64*)   (ws + 125437184);           // 8*512*8 = 32,768
    u64*    l3out = (u64*)   (ws + 125469952);           // 512*8 = 4,096
    u64*    mats  = (u64*)   (ws + 125474048);           // 2*512*8*8 = 65,536
    double* bxs   = (double*)(ws + 125539584);           // 5*512*8 = 20,480
    u64*    vwords= (u64*)   (ws + 125560064);           // 64
    double* boxpl = (double*)(ws + 127812864);           // NPIX*5*8 -> 41,534,720
    double* wd    = (double*)(ws + 169347584);           // WDTOT*8 = 53,056

    k_prep<<<1, 256, 0, stream>>>(w1, b1, p1, w2, b2, p2, w3, b3, p3, wa, ba, wb, bb, wd, ctrl, ghist);
    k_conv1f<<<dim3(16, 256), dim3(64, 4), 0, stream>>>(x, w1, b1, p1, Pf);
    k_conv2f<<<dim3(1, W2H), dim3(64, 4), 0, stream>>>(Pf, w2, b2, p2, H2f);
    k_conv3f<<<dim3(1, W3H), dim3(64, 8), 0, stream>>>(H2f, w3, b3, p3, wa, ba, Lg, ghist);
    k_select<<<1024, 256, 0, stream>>>(Lg, ghist, ctrl, selidx);
    k_recomp<<<2048, 64, 0, stream>>>(x, wd, selidx, ctrl, keys, boxpl);
    k_top8<<<8, 512, 0, stream>>>(keys, ctrl, lists8);
    k_mergefin<<<1, 512, 0, stream>>>(lists8, boxpl, l3out, bxs, vwords);
    k_boxmat<<<dim3(8, 2), 512, 0, stream>>>(l3out, boxpl, mats);
    k_nmsfin<<<1, 512, 0, stream>>>(mats, bxs, vwords, out);
}